// Round 1
// baseline (229.671 us; speedup 1.0000x reference)
//
#include <hip/hip_runtime.h>
#include <math.h>

#define TOKENS   4096          // B*T = 2*2048
#define CDIM     1024
#define NEXP     8
#define CAP      2048
#define OUT_OFS  8             // used_capacity occupies d_out[0..8)
#define PER_OUT  (TOKENS * NEXP * CAP)   // 67,108,864 elements per big output

// ---------------------------------------------------------------------------
// Kernel 1: zero-fill the two big outputs (contiguous region after the first
// 8 floats). 33,554,432 float4 stores.
// ---------------------------------------------------------------------------
__global__ __launch_bounds__(256) void fill_zero_kernel(float4* __restrict__ p, int n4) {
    int i = blockIdx.x * 256 + threadIdx.x;
    const int stride = gridDim.x * 256;
    const float4 z = make_float4(0.f, 0.f, 0.f, 0.f);
    for (; i < n4; i += stride) p[i] = z;
}

// ---------------------------------------------------------------------------
// Kernel 2: gating. One wave per token. logits[e] = dot(x[t], w_g[e]).
// Top-2 (ties -> lower index, matching lax.top_k), softmax over the two.
// ---------------------------------------------------------------------------
__global__ __launch_bounds__(256) void gating_kernel(const float* __restrict__ x,
                                                     const float* __restrict__ wg,
                                                     int*   __restrict__ top1,
                                                     int*   __restrict__ top2,
                                                     float* __restrict__ p1,
                                                     float* __restrict__ p2) {
    __shared__ float swg[NEXP * CDIM];       // 32 KiB
    for (int i = threadIdx.x; i < NEXP * CDIM / 4; i += 256)
        ((float4*)swg)[i] = ((const float4*)wg)[i];
    __syncthreads();

    const int wave = threadIdx.x >> 6;
    const int lane = threadIdx.x & 63;
    const int tok  = blockIdx.x * 4 + wave;
    const float* xr = x + (size_t)tok * CDIM;

    float acc[NEXP];
#pragma unroll
    for (int e = 0; e < NEXP; ++e) acc[e] = 0.f;

#pragma unroll
    for (int i = 0; i < CDIM / 64; ++i) {
        const float xv = xr[lane + 64 * i];
#pragma unroll
        for (int e = 0; e < NEXP; ++e)
            acc[e] = fmaf(xv, swg[e * CDIM + lane + 64 * i], acc[e]);
    }
    // 64-lane tree reduction per expert (well-conditioned, ~1e-6 abs err)
#pragma unroll
    for (int e = 0; e < NEXP; ++e) {
        float v = acc[e];
#pragma unroll
        for (int s = 32; s >= 1; s >>= 1) v += __shfl_xor(v, s, 64);
        acc[e] = v;
    }

    if (lane == 0) {
        int e1 = 0; float l1 = acc[0];
#pragma unroll
        for (int e = 1; e < NEXP; ++e)
            if (acc[e] > l1) { l1 = acc[e]; e1 = e; }
        int e2 = -1; float l2 = -INFINITY;
#pragma unroll
        for (int e = 0; e < NEXP; ++e)
            if (e != e1 && acc[e] > l2) { l2 = acc[e]; e2 = e; }
        // softmax over {l1, l2} with max subtraction (l1 >= l2)
        const float ex = expf(l2 - l1);
        const float denom = 1.f + ex;
        top1[tok] = e1;
        top2[tok] = e2;
        p1[tok] = 1.f / denom;
        p2[tok] = ex / denom;
    }
}

// ---------------------------------------------------------------------------
// Kernel 3: capacity scan + scatter. Single wave; global assignment order is
// a = k*TOKENS + t (k-major, then token), lane i owns the contiguous chunk
// [i*128, (i+1)*128) so global order is preserved. Per-expert counters are
// kept in registers via static-index predicated updates (no scratch).
// ---------------------------------------------------------------------------
__global__ __launch_bounds__(64) void scan_scatter_kernel(const int* __restrict__ top1,
                                                          const int* __restrict__ top2,
                                                          const float* __restrict__ p1,
                                                          const float* __restrict__ p2,
                                                          float* __restrict__ out) {
    const int lane = threadIdx.x;          // 0..63
    const int base = lane * 128;           // 8192 assignments / 64 lanes

    int c[NEXP];
#pragma unroll
    for (int e = 0; e < NEXP; ++e) c[e] = 0;

    for (int j = 0; j < 128; ++j) {
        const int a = base + j;
        const int e = (a < TOKENS) ? top1[a] : top2[a - TOKENS];
#pragma unroll
        for (int ee = 0; ee < NEXP; ++ee) c[ee] += (e == ee);
    }

    // per-expert exclusive prefix across lanes + totals
    int off[NEXP], tot[NEXP];
#pragma unroll
    for (int e = 0; e < NEXP; ++e) {
        int v = c[e];
#pragma unroll
        for (int s = 1; s <= 32; s <<= 1) {
            const int u = __shfl_up(v, s, 64);
            if (lane >= s) v += u;
        }
        off[e] = v - c[e];
        tot[e] = __shfl(v, 63, 64);
    }

    float* __restrict__ cb = out + OUT_OFS;
    float* __restrict__ mk = out + OUT_OFS + (size_t)PER_OUT;

    for (int j = 0; j < 128; ++j) {
        const int a = base + j;
        int t, e; float p;
        if (a < TOKENS) { t = a;          e = top1[t]; p = p1[t]; }
        else            { t = a - TOKENS; e = top2[t]; p = p2[t]; }
        int r = 0;
#pragma unroll
        for (int ee = 0; ee < NEXP; ++ee) {
            if (e == ee) { r = off[ee]; off[ee] = r + 1; }
        }
        if (r < CAP) {
            const size_t idx = ((size_t)t * NEXP + e) * CAP + r;
            cb[idx] = p;
            mk[idx] = (p != 0.f) ? 1.f : 0.f;   // sec_mask = bool(cb_weight)
        }
    }

    if (lane < NEXP)
        out[lane] = (float)(tot[lane] < CAP ? tot[lane] : CAP);
}

// ---------------------------------------------------------------------------
extern "C" void kernel_launch(void* const* d_in, const int* in_sizes, int n_in,
                              void* d_out, int out_size, void* d_ws, size_t ws_size,
                              hipStream_t stream) {
    const float* x  = (const float*)d_in[0];
    const float* wg = (const float*)d_in[1];
    float* out = (float*)d_out;

    int*   top1 = (int*)d_ws;
    int*   top2 = top1 + TOKENS;
    float* p1   = (float*)(top2 + TOKENS);
    float* p2   = p1 + TOKENS;

    // 1) zero the two big outputs (contiguous: d_out+8 .. d_out+8+2*PER_OUT)
    const int n4 = (2 * PER_OUT) / 4;   // 33,554,432 float4
    fill_zero_kernel<<<2048, 256, 0, stream>>>((float4*)(out + OUT_OFS), n4);

    // 2) gating: 4 tokens per 256-thread block
    gating_kernel<<<TOKENS / 4, 256, 0, stream>>>(x, wg, top1, top2, p1, p2);

    // 3) sequential-order capacity scan + scatter + used_capacity
    scan_scatter_kernel<<<1, 64, 0, stream>>>(top1, top2, p1, p2, out);
}

// Round 2
// 169.738 us; speedup vs baseline: 1.3531x; 1.3531x over previous
//
#include <hip/hip_runtime.h>
#include <math.h>

#define TOKENS   4096          // B*T = 2*2048
#define CDIM     1024
#define NEXP     8
#define CAP      2048
#define OUT_OFS  8             // used_capacity occupies d_out[0..8)
#define PER_OUT  (TOKENS * NEXP * CAP)   // 67,108,864 elements per big output

// ---------------------------------------------------------------------------
// Kernel 1: gating. One wave per token. logits[e] = dot(x[t], w_g[e]).
// Top-2 (ties -> lower index, matching lax.top_k), softmax over the two.
// ---------------------------------------------------------------------------
__global__ __launch_bounds__(256) void gating_kernel(const float* __restrict__ x,
                                                     const float* __restrict__ wg,
                                                     int*   __restrict__ top1,
                                                     int*   __restrict__ top2,
                                                     float* __restrict__ p1,
                                                     float* __restrict__ p2) {
    __shared__ float swg[NEXP * CDIM];       // 32 KiB
    for (int i = threadIdx.x; i < NEXP * CDIM / 4; i += 256)
        ((float4*)swg)[i] = ((const float4*)wg)[i];
    __syncthreads();

    const int wave = threadIdx.x >> 6;
    const int lane = threadIdx.x & 63;
    const int tok  = blockIdx.x * 4 + wave;
    const float* xr = x + (size_t)tok * CDIM;

    float acc[NEXP];
#pragma unroll
    for (int e = 0; e < NEXP; ++e) acc[e] = 0.f;

#pragma unroll
    for (int i = 0; i < CDIM / 64; ++i) {
        const float xv = xr[lane + 64 * i];
#pragma unroll
        for (int e = 0; e < NEXP; ++e)
            acc[e] = fmaf(xv, swg[e * CDIM + lane + 64 * i], acc[e]);
    }
    // 64-lane tree reduction per expert (well-conditioned, ~1e-6 abs err)
#pragma unroll
    for (int e = 0; e < NEXP; ++e) {
        float v = acc[e];
#pragma unroll
        for (int s = 32; s >= 1; s >>= 1) v += __shfl_xor(v, s, 64);
        acc[e] = v;
    }

    if (lane == 0) {
        int e1 = 0; float l1 = acc[0];
#pragma unroll
        for (int e = 1; e < NEXP; ++e)
            if (acc[e] > l1) { l1 = acc[e]; e1 = e; }
        int e2 = -1; float l2 = -INFINITY;
#pragma unroll
        for (int e = 0; e < NEXP; ++e)
            if (e != e1 && acc[e] > l2) { l2 = acc[e]; e2 = e; }
        // softmax over {l1, l2} with max subtraction (l1 >= l2)
        const float ex = expf(l2 - l1);
        const float denom = 1.f + ex;
        top1[tok] = e1;
        top2[tok] = e2;
        p1[tok] = 1.f / denom;
        p2[tok] = ex / denom;
    }
}

// ---------------------------------------------------------------------------
// Kernel 2: capacity scan (ranks only). Single wave; global assignment order
// is a = k*TOKENS + t (k-major, then token); lane i owns the contiguous chunk
// [i*128, (i+1)*128) so global order is preserved. Per-expert counters are
// kept in registers via static-index predicated updates (rule #20).
// Outputs raw ranks r1[t], r2[t] (write kernel applies the CAP check) and
// used_capacity into out[0..8).
// ---------------------------------------------------------------------------
__global__ __launch_bounds__(64) void scan_kernel(const int* __restrict__ top1,
                                                  const int* __restrict__ top2,
                                                  int* __restrict__ r1,
                                                  int* __restrict__ r2,
                                                  float* __restrict__ out) {
    const int lane = threadIdx.x;          // 0..63
    const int base = lane * 128;           // 8192 assignments / 64 lanes

    int c[NEXP];
#pragma unroll
    for (int e = 0; e < NEXP; ++e) c[e] = 0;

    for (int j = 0; j < 128; ++j) {
        const int a = base + j;
        const int e = (a < TOKENS) ? top1[a] : top2[a - TOKENS];
#pragma unroll
        for (int ee = 0; ee < NEXP; ++ee) c[ee] += (e == ee);
    }

    // per-expert exclusive prefix across lanes + totals
    int off[NEXP], tot[NEXP];
#pragma unroll
    for (int e = 0; e < NEXP; ++e) {
        int v = c[e];
#pragma unroll
        for (int s = 1; s <= 32; s <<= 1) {
            const int u = __shfl_up(v, s, 64);
            if (lane >= s) v += u;
        }
        off[e] = v - c[e];
        tot[e] = __shfl(v, 63, 64);
    }

    // replay in order, emitting each assignment's rank
    for (int j = 0; j < 128; ++j) {
        const int a = base + j;
        const int e = (a < TOKENS) ? top1[a] : top2[a - TOKENS];
        int r = 0;
#pragma unroll
        for (int ee = 0; ee < NEXP; ++ee) {
            if (e == ee) { r = off[ee]; off[ee] = r + 1; }
        }
        if (a < TOKENS) r1[a] = r;
        else            r2[a - TOKENS] = r;
    }

    if (lane < NEXP)
        out[lane] = (float)(tot[lane] < CAP ? tot[lane] : CAP);
}

// ---------------------------------------------------------------------------
// Kernel 3: streaming final-value write. One block per (t,e) row; each row of
// cb_weight (2048 floats) and sec_mask (2048 floats) has at most ONE nonzero
// (top1 != top2, one rank per pair). Pure coalesced float4 stores, no
// zero-fill + scatter read-modify-write.
// ---------------------------------------------------------------------------
__global__ __launch_bounds__(256) void write_kernel(const int* __restrict__ top1,
                                                    const int* __restrict__ top2,
                                                    const float* __restrict__ p1,
                                                    const float* __restrict__ p2,
                                                    const int* __restrict__ r1,
                                                    const int* __restrict__ r2,
                                                    float* __restrict__ out) {
    const int row = blockIdx.x;            // t*NEXP + e
    const int t = row >> 3;
    const int e = row & 7;

    int slot = -1; float p = 0.f;
    const int e1 = top1[t];
    const int e2 = top2[t];
    if (e == e1) { const int r = r1[t]; if (r < CAP) { slot = r; p = p1[t]; } }
    else if (e == e2) { const int r = r2[t]; if (r < CAP) { slot = r; p = p2[t]; } }
    const float mval = (p != 0.f) ? 1.f : 0.f;   // sec_mask = bool(cb_weight)

    float4* __restrict__ cb = (float4*)(out + OUT_OFS) + (size_t)row * (CAP / 4);
    float4* __restrict__ mk = (float4*)(out + OUT_OFS + (size_t)PER_OUT) + (size_t)row * (CAP / 4);

#pragma unroll
    for (int k = 0; k < CAP / 4 / 256; ++k) {
        const int i = k * 256 + threadIdx.x;
        const int j = i * 4;
        float4 v = make_float4(0.f, 0.f, 0.f, 0.f);
        float4 m = make_float4(0.f, 0.f, 0.f, 0.f);
        if (slot >= j && slot < j + 4) {
            ((float*)&v)[slot - j] = p;
            ((float*)&m)[slot - j] = mval;
        }
        cb[i] = v;
        mk[i] = m;
    }
}

// ---------------------------------------------------------------------------
extern "C" void kernel_launch(void* const* d_in, const int* in_sizes, int n_in,
                              void* d_out, int out_size, void* d_ws, size_t ws_size,
                              hipStream_t stream) {
    const float* x  = (const float*)d_in[0];
    const float* wg = (const float*)d_in[1];
    float* out = (float*)d_out;

    int*   top1 = (int*)d_ws;
    int*   top2 = top1 + TOKENS;
    int*   r1   = top2 + TOKENS;
    int*   r2   = r1 + TOKENS;
    float* p1   = (float*)(r2 + TOKENS);
    float* p2   = p1 + TOKENS;

    // 1) gating: 4 tokens per 256-thread block
    gating_kernel<<<TOKENS / 4, 256, 0, stream>>>(x, wg, top1, top2, p1, p2);

    // 2) sequential-order capacity scan -> ranks + used_capacity
    scan_kernel<<<1, 64, 0, stream>>>(top1, top2, r1, r2, out);

    // 3) stream the final big outputs (one block per (t,e) row)
    write_kernel<<<TOKENS * NEXP, 256, 0, stream>>>(top1, top2, p1, p2, r1, r2, out);
}

// Round 4
// 167.429 us; speedup vs baseline: 1.3717x; 1.0138x over previous
//
#include <hip/hip_runtime.h>
#include <math.h>

#define TOKENS   4096          // B*T = 2*2048
#define CDIM     1024
#define NEXP     8
#define CAP      2048
#define OUT_OFS  8             // used_capacity occupies d_out[0..8)
#define PER_OUT  (TOKENS * NEXP * CAP)   // 67,108,864 elements per big output

typedef float f32x4 __attribute__((ext_vector_type(4)));   // native vec for nontemporal stores

// ---------------------------------------------------------------------------
// Kernel 1: gating. One wave per token. logits[e] = dot(x[t], w_g[e]).
// Top-2 (ties -> lower index, matching lax.top_k), softmax over the two.
// ---------------------------------------------------------------------------
__global__ __launch_bounds__(256) void gating_kernel(const float* __restrict__ x,
                                                     const float* __restrict__ wg,
                                                     int*   __restrict__ top1,
                                                     int*   __restrict__ top2,
                                                     float* __restrict__ p1,
                                                     float* __restrict__ p2) {
    __shared__ float swg[NEXP * CDIM];       // 32 KiB
    for (int i = threadIdx.x; i < NEXP * CDIM / 4; i += 256)
        ((float4*)swg)[i] = ((const float4*)wg)[i];
    __syncthreads();

    const int wave = threadIdx.x >> 6;
    const int lane = threadIdx.x & 63;
    const int tok  = blockIdx.x * 4 + wave;
    const float* xr = x + (size_t)tok * CDIM;

    float acc[NEXP];
#pragma unroll
    for (int e = 0; e < NEXP; ++e) acc[e] = 0.f;

#pragma unroll
    for (int i = 0; i < CDIM / 64; ++i) {
        const float xv = xr[lane + 64 * i];
#pragma unroll
        for (int e = 0; e < NEXP; ++e)
            acc[e] = fmaf(xv, swg[e * CDIM + lane + 64 * i], acc[e]);
    }
    // 64-lane tree reduction per expert (well-conditioned, ~1e-6 abs err)
#pragma unroll
    for (int e = 0; e < NEXP; ++e) {
        float v = acc[e];
#pragma unroll
        for (int s = 32; s >= 1; s >>= 1) v += __shfl_xor(v, s, 64);
        acc[e] = v;
    }

    if (lane == 0) {
        int e1 = 0; float l1 = acc[0];
#pragma unroll
        for (int e = 1; e < NEXP; ++e)
            if (acc[e] > l1) { l1 = acc[e]; e1 = e; }
        int e2 = -1; float l2 = -INFINITY;
#pragma unroll
        for (int e = 0; e < NEXP; ++e)
            if (e != e1 && acc[e] > l2) { l2 = acc[e]; e2 = e; }
        // softmax over {l1, l2} with max subtraction (l1 >= l2)
        const float ex = expf(l2 - l1);
        const float denom = 1.f + ex;
        top1[tok] = e1;
        top2[tok] = e2;
        p1[tok] = 1.f / denom;
        p2[tok] = ex / denom;
    }
}

// ---------------------------------------------------------------------------
// Kernel 2: capacity scan (ranks only), latency-optimized. Single wave;
// global assignment order is a = k*TOKENS + t; lane i owns the contiguous
// chunk [i*128, (i+1)*128). Lanes 0..31 cover top1 entirely, 32..63 top2.
// All 128 expert-ids are loaded up-front with 32 unrolled int4 loads (one
// vmcnt drain total, not one per iteration), counted via a packed 8x8-bit
// 64-bit histogram, then replayed from registers. Ranks written back as int4.
// ---------------------------------------------------------------------------
__global__ __launch_bounds__(64) void scan_kernel(const int* __restrict__ top1,
                                                  const int* __restrict__ top2,
                                                  int* __restrict__ r1,
                                                  int* __restrict__ r2,
                                                  float* __restrict__ out) {
    const int lane = threadIdx.x;          // 0..63
    const int* __restrict__ src = (lane < 32) ? (top1 + lane * 128)
                                              : (top2 + (lane - 32) * 128);
    int4 a[32];
#pragma unroll
    for (int i = 0; i < 32; ++i) a[i] = ((const int4*)src)[i];

    // packed histogram: 8 experts x 8 bits (max 128 per lane fits)
    unsigned long long cnt = 0ull;
#pragma unroll
    for (int i = 0; i < 32; ++i) {
        cnt += 1ull << (a[i].x << 3);
        cnt += 1ull << (a[i].y << 3);
        cnt += 1ull << (a[i].z << 3);
        cnt += 1ull << (a[i].w << 3);
    }
    int c[NEXP];
#pragma unroll
    for (int e = 0; e < NEXP; ++e) c[e] = (int)((cnt >> (e * 8)) & 0xff);

    // per-expert exclusive prefix across lanes + totals
    int off[NEXP], tot[NEXP];
#pragma unroll
    for (int e = 0; e < NEXP; ++e) {
        int v = c[e];
#pragma unroll
        for (int s = 1; s <= 32; s <<= 1) {
            const int u = __shfl_up(v, s, 64);
            if (lane >= s) v += u;
        }
        off[e] = v - c[e];
        tot[e] = __shfl(v, 63, 64);
    }

    // replay from registers, emitting ranks packed as int4
    int* __restrict__ dst = (lane < 32) ? (r1 + lane * 128)
                                        : (r2 + (lane - 32) * 128);
#pragma unroll
    for (int i = 0; i < 32; ++i) {
        int4 r;
        int e, rr;
        e = a[i].x; rr = 0;
#pragma unroll
        for (int ee = 0; ee < NEXP; ++ee) if (e == ee) { rr = off[ee]; off[ee] = rr + 1; }
        r.x = rr;
        e = a[i].y; rr = 0;
#pragma unroll
        for (int ee = 0; ee < NEXP; ++ee) if (e == ee) { rr = off[ee]; off[ee] = rr + 1; }
        r.y = rr;
        e = a[i].z; rr = 0;
#pragma unroll
        for (int ee = 0; ee < NEXP; ++ee) if (e == ee) { rr = off[ee]; off[ee] = rr + 1; }
        r.z = rr;
        e = a[i].w; rr = 0;
#pragma unroll
        for (int ee = 0; ee < NEXP; ++ee) if (e == ee) { rr = off[ee]; off[ee] = rr + 1; }
        r.w = rr;
        ((int4*)dst)[i] = r;
    }

    if (lane < NEXP)
        out[lane] = (float)(tot[lane] < CAP ? tot[lane] : CAP);
}

// ---------------------------------------------------------------------------
// Kernel 3: streaming final-value write. One block per token (8 rows of
// cb_weight + 8 rows of sec_mask, 32 KB per block). Each (t,e) row has at
// most ONE nonzero. Pure coalesced nontemporal float4 stores.
// ---------------------------------------------------------------------------
__global__ __launch_bounds__(256) void write_kernel(const int* __restrict__ top1,
                                                    const int* __restrict__ top2,
                                                    const float* __restrict__ p1,
                                                    const float* __restrict__ p2,
                                                    const int* __restrict__ r1,
                                                    const int* __restrict__ r2,
                                                    float* __restrict__ out) {
    const int t = blockIdx.x;
    const int e1 = top1[t];
    const int e2 = top2[t];
    const int rr1 = r1[t];
    const int rr2 = r2[t];
    const float pp1 = p1[t];
    const float pp2 = p2[t];
    const int s1 = (rr1 < CAP) ? rr1 : -1;
    const int s2 = (rr2 < CAP) ? rr2 : -1;

    f32x4* __restrict__ cb = (f32x4*)(out + OUT_OFS) + (size_t)t * (NEXP * CAP / 4);
    f32x4* __restrict__ mk = (f32x4*)(out + OUT_OFS + (size_t)PER_OUT) + (size_t)t * (NEXP * CAP / 4);

#pragma unroll
    for (int k = 0; k < NEXP * CAP / 4 / 256; ++k) {   // 16 iterations
        const int i = k * 256 + threadIdx.x;           // float4 index within token
        const int e = i >> 9;                          // 512 float4 per row
        const int j = (i & 511) << 2;                  // float offset within row
        f32x4 v = (f32x4)(0.f);
        f32x4 m = (f32x4)(0.f);
        int slot = -1; float p = 0.f;
        if (e == e1) { slot = s1; p = pp1; }
        if (e == e2) { slot = s2; p = pp2; }
        const int d = slot - j;
        if (d >= 0 && d < 4) {
            v[d] = p;
            m[d] = (p != 0.f) ? 1.f : 0.f;             // sec_mask = bool(cb_weight)
        }
        __builtin_nontemporal_store(v, &cb[i]);
        __builtin_nontemporal_store(m, &mk[i]);
    }
}

// ---------------------------------------------------------------------------
extern "C" void kernel_launch(void* const* d_in, const int* in_sizes, int n_in,
                              void* d_out, int out_size, void* d_ws, size_t ws_size,
                              hipStream_t stream) {
    const float* x  = (const float*)d_in[0];
    const float* wg = (const float*)d_in[1];
    float* out = (float*)d_out;

    int*   top1 = (int*)d_ws;
    int*   top2 = top1 + TOKENS;
    int*   r1   = top2 + TOKENS;
    int*   r2   = r1 + TOKENS;
    float* p1   = (float*)(r2 + TOKENS);
    float* p2   = p1 + TOKENS;

    // 1) gating: 4 tokens per 256-thread block
    gating_kernel<<<TOKENS / 4, 256, 0, stream>>>(x, wg, top1, top2, p1, p2);

    // 2) sequential-order capacity scan -> ranks + used_capacity
    scan_kernel<<<1, 64, 0, stream>>>(top1, top2, r1, r2, out);

    // 3) stream the final big outputs (one block per token)
    write_kernel<<<TOKENS, 256, 0, stream>>>(top1, top2, p1, p2, r1, r2, out);
}

// Round 5
// 143.433 us; speedup vs baseline: 1.6012x; 1.1673x over previous
//
#include <hip/hip_runtime.h>
#include <math.h>

#define TOKENS   4096          // B*T = 2*2048
#define CDIM     1024
#define NEXP     8
#define CAP      2048
#define OUT_OFS  8             // used_capacity occupies d_out[0..8)
#define PER_OUT  (TOKENS * NEXP * CAP)   // 67,108,864 elements per big output

// ---------------------------------------------------------------------------
// Kernel 1: gating. One wave per token. logits[e] = dot(x[t], w_g[e]).
// Top-2 (ties -> lower index, matching lax.top_k), softmax over the two.
// ---------------------------------------------------------------------------
__global__ __launch_bounds__(256) void gating_kernel(const float* __restrict__ x,
                                                     const float* __restrict__ wg,
                                                     int*   __restrict__ top1,
                                                     int*   __restrict__ top2,
                                                     float* __restrict__ p1,
                                                     float* __restrict__ p2) {
    __shared__ float swg[NEXP * CDIM];       // 32 KiB
    for (int i = threadIdx.x; i < NEXP * CDIM / 4; i += 256)
        ((float4*)swg)[i] = ((const float4*)wg)[i];
    __syncthreads();

    const int wave = threadIdx.x >> 6;
    const int lane = threadIdx.x & 63;
    const int tok  = blockIdx.x * 4 + wave;
    const float* xr = x + (size_t)tok * CDIM;

    float acc[NEXP];
#pragma unroll
    for (int e = 0; e < NEXP; ++e) acc[e] = 0.f;

#pragma unroll
    for (int i = 0; i < CDIM / 64; ++i) {
        const float xv = xr[lane + 64 * i];
#pragma unroll
        for (int e = 0; e < NEXP; ++e)
            acc[e] = fmaf(xv, swg[e * CDIM + lane + 64 * i], acc[e]);
    }
    // 64-lane tree reduction per expert (well-conditioned, ~1e-6 abs err)
#pragma unroll
    for (int e = 0; e < NEXP; ++e) {
        float v = acc[e];
#pragma unroll
        for (int s = 32; s >= 1; s >>= 1) v += __shfl_xor(v, s, 64);
        acc[e] = v;
    }

    if (lane == 0) {
        int e1 = 0; float l1 = acc[0];
#pragma unroll
        for (int e = 1; e < NEXP; ++e)
            if (acc[e] > l1) { l1 = acc[e]; e1 = e; }
        int e2 = -1; float l2 = -INFINITY;
#pragma unroll
        for (int e = 0; e < NEXP; ++e)
            if (e != e1 && acc[e] > l2) { l2 = acc[e]; e2 = e; }
        // softmax over {l1, l2} with max subtraction (l1 >= l2)
        const float ex = expf(l2 - l1);
        const float denom = 1.f + ex;
        top1[tok] = e1;
        top2[tok] = e2;
        p1[tok] = 1.f / denom;
        p2[tok] = ex / denom;
    }
}

// ---------------------------------------------------------------------------
// Kernel 2: capacity scan (ranks only), latency-optimized. Single wave;
// global assignment order is a = k*TOKENS + t; lane i owns the contiguous
// chunk [i*128, (i+1)*128). Lanes 0..31 cover top1 entirely, 32..63 top2.
// All 128 expert-ids are loaded up-front with 32 unrolled int4 loads (one
// vmcnt drain total), counted via a packed 8x8-bit 64-bit histogram, then
// replayed from registers. Ranks written back as int4.
// ---------------------------------------------------------------------------
__global__ __launch_bounds__(64) void scan_kernel(const int* __restrict__ top1,
                                                  const int* __restrict__ top2,
                                                  int* __restrict__ r1,
                                                  int* __restrict__ r2,
                                                  float* __restrict__ out) {
    const int lane = threadIdx.x;          // 0..63
    const int* __restrict__ src = (lane < 32) ? (top1 + lane * 128)
                                              : (top2 + (lane - 32) * 128);
    int4 a[32];
#pragma unroll
    for (int i = 0; i < 32; ++i) a[i] = ((const int4*)src)[i];

    // packed histogram: 8 experts x 8 bits (max 128 per lane fits)
    unsigned long long cnt = 0ull;
#pragma unroll
    for (int i = 0; i < 32; ++i) {
        cnt += 1ull << (a[i].x << 3);
        cnt += 1ull << (a[i].y << 3);
        cnt += 1ull << (a[i].z << 3);
        cnt += 1ull << (a[i].w << 3);
    }
    int c[NEXP];
#pragma unroll
    for (int e = 0; e < NEXP; ++e) c[e] = (int)((cnt >> (e * 8)) & 0xff);

    // per-expert exclusive prefix across lanes + totals
    int off[NEXP], tot[NEXP];
#pragma unroll
    for (int e = 0; e < NEXP; ++e) {
        int v = c[e];
#pragma unroll
        for (int s = 1; s <= 32; s <<= 1) {
            const int u = __shfl_up(v, s, 64);
            if (lane >= s) v += u;
        }
        off[e] = v - c[e];
        tot[e] = __shfl(v, 63, 64);
    }

    // replay from registers, emitting ranks packed as int4
    int* __restrict__ dst = (lane < 32) ? (r1 + lane * 128)
                                        : (r2 + (lane - 32) * 128);
#pragma unroll
    for (int i = 0; i < 32; ++i) {
        int4 r;
        int e, rr;
        e = a[i].x; rr = 0;
#pragma unroll
        for (int ee = 0; ee < NEXP; ++ee) if (e == ee) { rr = off[ee]; off[ee] = rr + 1; }
        r.x = rr;
        e = a[i].y; rr = 0;
#pragma unroll
        for (int ee = 0; ee < NEXP; ++ee) if (e == ee) { rr = off[ee]; off[ee] = rr + 1; }
        r.y = rr;
        e = a[i].z; rr = 0;
#pragma unroll
        for (int ee = 0; ee < NEXP; ++ee) if (e == ee) { rr = off[ee]; off[ee] = rr + 1; }
        r.z = rr;
        e = a[i].w; rr = 0;
#pragma unroll
        for (int ee = 0; ee < NEXP; ++ee) if (e == ee) { rr = off[ee]; off[ee] = rr + 1; }
        r.w = rr;
        ((int4*)dst)[i] = r;
    }

    if (lane < NEXP)
        out[lane] = (float)(tot[lane] < CAP ? tot[lane] : CAP);
}

// ---------------------------------------------------------------------------
// Kernel 3: streaming final-value write. One block per token (8 rows of
// cb_weight + 8 rows of sec_mask, 128 KB per block). Each (t,e) row has at
// most ONE nonzero. Pure coalesced float4 stores (plain — L2 write-combining;
// nontemporal regressed ~60 us in round 4).
// ---------------------------------------------------------------------------
__global__ __launch_bounds__(256) void write_kernel(const int* __restrict__ top1,
                                                    const int* __restrict__ top2,
                                                    const float* __restrict__ p1,
                                                    const float* __restrict__ p2,
                                                    const int* __restrict__ r1,
                                                    const int* __restrict__ r2,
                                                    float* __restrict__ out) {
    const int t = blockIdx.x;
    const int e1 = top1[t];
    const int e2 = top2[t];
    const int rr1 = r1[t];
    const int rr2 = r2[t];
    const float pp1 = p1[t];
    const float pp2 = p2[t];
    const int s1 = (rr1 < CAP) ? rr1 : -1;
    const int s2 = (rr2 < CAP) ? rr2 : -1;

    float4* __restrict__ cb = (float4*)(out + OUT_OFS) + (size_t)t * (NEXP * CAP / 4);
    float4* __restrict__ mk = (float4*)(out + OUT_OFS + (size_t)PER_OUT) + (size_t)t * (NEXP * CAP / 4);

#pragma unroll
    for (int k = 0; k < NEXP * CAP / 4 / 256; ++k) {   // 16 iterations
        const int i = k * 256 + threadIdx.x;           // float4 index within token
        const int e = i >> 9;                          // 512 float4 per row
        const int j = (i & 511) << 2;                  // float offset within row
        float4 v = make_float4(0.f, 0.f, 0.f, 0.f);
        float4 m = make_float4(0.f, 0.f, 0.f, 0.f);
        int slot = -1; float p = 0.f;
        if (e == e1) { slot = s1; p = pp1; }
        if (e == e2) { slot = s2; p = pp2; }
        const int d = slot - j;
        if (d >= 0 && d < 4) {
            ((float*)&v)[d] = p;
            ((float*)&m)[d] = (p != 0.f) ? 1.f : 0.f;  // sec_mask = bool(cb_weight)
        }
        cb[i] = v;
        mk[i] = m;
    }
}

// ---------------------------------------------------------------------------
extern "C" void kernel_launch(void* const* d_in, const int* in_sizes, int n_in,
                              void* d_out, int out_size, void* d_ws, size_t ws_size,
                              hipStream_t stream) {
    const float* x  = (const float*)d_in[0];
    const float* wg = (const float*)d_in[1];
    float* out = (float*)d_out;

    int*   top1 = (int*)d_ws;
    int*   top2 = top1 + TOKENS;
    int*   r1   = top2 + TOKENS;
    int*   r2   = r1 + TOKENS;
    float* p1   = (float*)(r2 + TOKENS);
    float* p2   = p1 + TOKENS;

    // 1) gating: 4 tokens per 256-thread block
    gating_kernel<<<TOKENS / 4, 256, 0, stream>>>(x, wg, top1, top2, p1, p2);

    // 2) sequential-order capacity scan -> ranks + used_capacity
    scan_kernel<<<1, 64, 0, stream>>>(top1, top2, r1, r2, out);

    // 3) stream the final big outputs (one block per token)
    write_kernel<<<TOKENS, 256, 0, stream>>>(top1, top2, p1, p2, r1, r2, out);
}